// Round 1
// baseline (373.519 us; speedup 1.0000x reference)
//
#include <hip/hip_runtime.h>

#define BB 128
#define NN 500
#define CC 80
#define NH 6

// keep[n] = max_c predicted_class[-1][0][n][c] > 0  (sigmoid(x)>0.5 <=> x>0)
__global__ void keep_kernel(const float* __restrict__ pc, int* __restrict__ keep) {
    int n = blockIdx.x * blockDim.x + threadIdx.x;
    if (n >= NN) return;
    const float* row = pc + (size_t)(NH - 1) * BB * NN * CC + (size_t)n * CC;
    float m = row[0];
    for (int c = 1; c < CC; ++c) m = fmaxf(m, row[c]);
    keep[n] = (m > 0.0f) ? 1 : 0;
}

// boxes_next over B*N items (2 coords each)
__global__ void boxes_next_kernel(const float* __restrict__ boxes_t,
                                  const float* __restrict__ pb,
                                  const float* __restrict__ noise,
                                  const float* __restrict__ fresh,
                                  const float* __restrict__ ac,
                                  const int* __restrict__ t_now_p,
                                  const int* __restrict__ t_next_p,
                                  const int* __restrict__ keep,
                                  float* __restrict__ out) {
    int i = blockIdx.x * blockDim.x + threadIdx.x;
    if (i >= BB * NN) return;
    int n = i % NN;
    int tn = t_now_p[0], tx = t_next_p[0];
    float a = ac[tn], an = ac[tx];
    float sqrt_recip = sqrtf(1.0f / a);
    float sqrt_recipm1 = sqrtf(1.0f / a - 1.0f);
    float sigma = sqrtf((1.0f - a / an) * (1.0f - an) / (1.0f - a));
    float cc = sqrtf(1.0f - an - sigma * sigma);
    float sqan = sqrtf(an);
    const float2 bt = ((const float2*)boxes_t)[i];
    const float2 bs = ((const float2*)(pb + (size_t)(NH - 1) * BB * NN * 2))[i];
    float2 o;
    if (keep[n]) {
        const float2 nz = ((const float2*)noise)[i];
        float pn0 = (sqrt_recip * bt.x - bs.x) / sqrt_recipm1;
        float pn1 = (sqrt_recip * bt.y - bs.y) / sqrt_recipm1;
        o.x = bs.x * sqan + cc * pn0 + sigma * nz.x;
        o.y = bs.y * sqan + cc * pn1 + sigma * nz.y;
    } else {
        o = ((const float2*)fresh)[i];
    }
    ((float2*)out)[i] = o;
}

// scores / labels over B*N rows of C=80 logits.
// softmax then max over first 79 == exp(best79 - m)/sumexp(all 80)
__global__ void scores_labels_kernel(const float* __restrict__ pc,
                                     float* __restrict__ scores,
                                     float* __restrict__ labels) {
    int i = blockIdx.x * blockDim.x + threadIdx.x;
    if (i >= BB * NN) return;
    const float* row = pc + (size_t)(NH - 1) * BB * NN * CC + (size_t)i * CC;
    float m = row[0];
    for (int c = 1; c < CC; ++c) m = fmaxf(m, row[c]);
    float sum = 0.0f;
    float best = -3.4e38f;
    int bestc = 0;
    for (int c = 0; c < CC; ++c) {
        float v = row[c];
        sum += expf(v - m);
        if (c < CC - 1 && v > best) { best = v; bestc = c; }  // strict > => first-max, matches jnp.argmax
    }
    scores[i] = expf(best - m) / sum;
    labels[i] = (float)bestc;
}

// one block per batch: stable descending sort by rank-count, then greedy suppression
__global__ __launch_bounds__(256) void nms_kernel(const float* __restrict__ pb,
                                                  const float* __restrict__ scores,
                                                  const float* __restrict__ labels,
                                                  float* __restrict__ keep_out) {
    __shared__ float x1s[NN], x2s[NN], wss[NN], scs[NN];
    __shared__ int labs[NN], order[NN];
    __shared__ unsigned char supp[NN];
    const int b = blockIdx.x;
    const int tid = threadIdx.x;
    const int nt = blockDim.x;

    const float2* boxes = (const float2*)(pb + (size_t)(NH - 1) * BB * NN * 2) + (size_t)b * NN;
    const float* sc = scores + (size_t)b * NN;
    const float* lb = labels + (size_t)b * NN;

    for (int i = tid; i < NN; i += nt) {
        float2 cw = boxes[i];
        float w = fmaxf(cw.y, 0.0001f);
        x1s[i] = cw.x - w / 2.0f;
        x2s[i] = cw.x + w / 2.0f;
        wss[i] = w;                 // union uses clamped w, matching reference
        scs[i] = sc[i];
        labs[i] = (int)lb[i];
        supp[i] = 0;
    }
    __syncthreads();

    // stable descending argsort via counting rank
    for (int i = tid; i < NN; i += nt) {
        float si = scs[i];
        int r = 0;
        for (int j = 0; j < NN; ++j) {
            float sj = scs[j];
            r += (sj > si) || (sj == si && j < i);
        }
        order[r] = i;
    }
    __syncthreads();

    // sequential greedy suppression in sorted domain
    for (int k = 0; k < NN - 1; ++k) {
        __syncthreads();   // makes iteration k-1's supp writes visible
        if (!supp[k]) {
            const int ik = order[k];
            const float xk1 = x1s[ik], xk2 = x2s[ik], wk = wss[ik];
            const int lk = labs[ik];
            for (int l = k + 1 + tid; l < NN; l += nt) {
                const int il = order[l];
                if (labs[il] != lk) continue;
                float inter = fminf(xk2, x2s[il]) - fmaxf(xk1, x1s[il]);
                inter = fmaxf(inter, 0.0f);
                float uni = wk + wss[il] - inter;
                float iou = inter / fmaxf(uni, 1e-9f);
                if (iou > 0.5f) supp[l] = 1;
            }
        }
    }
    __syncthreads();

    for (int k = tid; k < NN; k += nt) {
        keep_out[(size_t)b * NN + order[k]] = supp[k] ? 0.0f : 1.0f;
    }
}

extern "C" void kernel_launch(void* const* d_in, const int* in_sizes, int n_in,
                              void* d_out, int out_size, void* d_ws, size_t ws_size,
                              hipStream_t stream) {
    const float* boxes_t = (const float*)d_in[0];
    const float* pc      = (const float*)d_in[1];
    const float* pb      = (const float*)d_in[2];
    const float* noise   = (const float*)d_in[3];
    const float* fresh   = (const float*)d_in[4];
    const float* ac      = (const float*)d_in[5];
    const int*   t_now   = (const int*)d_in[6];
    const int*   t_next  = (const int*)d_in[7];

    float* out_boxes  = (float*)d_out;                    // 128000
    float* out_scores = out_boxes + (size_t)BB * NN * 2;  // 64000
    float* out_labels = out_scores + (size_t)BB * NN;     // 64000
    float* out_keep   = out_labels + (size_t)BB * NN;     // 64000

    int* keep_ws = (int*)d_ws;  // 500 ints

    keep_kernel<<<(NN + 255) / 256, 256, 0, stream>>>(pc, keep_ws);
    boxes_next_kernel<<<(BB * NN + 255) / 256, 256, 0, stream>>>(
        boxes_t, pb, noise, fresh, ac, t_now, t_next, keep_ws, out_boxes);
    scores_labels_kernel<<<(BB * NN + 255) / 256, 256, 0, stream>>>(pc, out_scores, out_labels);
    nms_kernel<<<BB, 256, 0, stream>>>(pb, out_scores, out_labels, out_keep);
}

// Round 2
// 309.726 us; speedup vs baseline: 1.2060x; 1.2060x over previous
//
#include <hip/hip_runtime.h>

#define BB 128
#define NN 500
#define CC 80
#define NH 6

typedef unsigned long long u64;

// ---------------------------------------------------------------------------
// scores/labels/keep fused. 4 threads per row, float4 loads (64B per quad).
// keep[n] = max_c logits(b=0,n,c) > 0  (sigmoid monotone)
// scores = max(softmax(row)[:79]); labels = argmax(softmax(row)[:79]) first-max
// ---------------------------------------------------------------------------
__global__ __launch_bounds__(256) void scores_labels_keep_kernel(
    const float* __restrict__ pc,
    float* __restrict__ scores,
    float* __restrict__ labels,
    int* __restrict__ keep) {
    const int rl = threadIdx.x >> 2;   // row within block, 0..63
    const int q = threadIdx.x & 3;     // quad lane, 0..3
    const int row = blockIdx.x * 64 + rl;
    if (row >= BB * NN) return;

    const float4* base = (const float4*)(pc + (size_t)(NH - 1) * BB * NN * CC);
    float4 v[5];
#pragma unroll
    for (int k = 0; k < 5; ++k) v[k] = base[(size_t)row * 20 + q + 4 * k];

    // max over all 80
    float m = v[0].x;
#pragma unroll
    for (int k = 0; k < 5; ++k) {
        m = fmaxf(m, v[k].x); m = fmaxf(m, v[k].y);
        m = fmaxf(m, v[k].z); m = fmaxf(m, v[k].w);
    }
    m = fmaxf(m, __shfl_xor(m, 1));
    m = fmaxf(m, __shfl_xor(m, 2));

    // sum of exp over all 80
    float s = 0.0f;
#pragma unroll
    for (int k = 0; k < 5; ++k) {
        s += expf(v[k].x - m); s += expf(v[k].y - m);
        s += expf(v[k].z - m); s += expf(v[k].w - m);
    }
    s += __shfl_xor(s, 1);
    s += __shfl_xor(s, 2);

    // first-max over c<79
    float bv = -3.4e38f; int bc = 1000;
#pragma unroll
    for (int k = 0; k < 5; ++k) {
        const float* vf = (const float*)&v[k];
#pragma unroll
        for (int j = 0; j < 4; ++j) {
            int c = (q + 4 * k) * 4 + j;
            float val = vf[j];
            if (c < CC - 1 && (val > bv || (val == bv && c < bc))) { bv = val; bc = c; }
        }
    }
#pragma unroll
    for (int off = 1; off < 4; off <<= 1) {
        float ov = __shfl_xor(bv, off);
        int oc = __shfl_xor(bc, off);
        if (ov > bv || (ov == bv && oc < bc)) { bv = ov; bc = oc; }
    }

    if (q == 0) {
        scores[row] = expf(bv - m) / s;
        labels[row] = (float)bc;
        if (row < NN) keep[row] = (m > 0.0f) ? 1 : 0;
    }
}

// ---------------------------------------------------------------------------
// boxes_next over B*N items (2 coords each)
// ---------------------------------------------------------------------------
__global__ void boxes_next_kernel(const float* __restrict__ boxes_t,
                                  const float* __restrict__ pb,
                                  const float* __restrict__ noise,
                                  const float* __restrict__ fresh,
                                  const float* __restrict__ ac,
                                  const int* __restrict__ t_now_p,
                                  const int* __restrict__ t_next_p,
                                  const int* __restrict__ keep,
                                  float* __restrict__ out) {
    int i = blockIdx.x * blockDim.x + threadIdx.x;
    if (i >= BB * NN) return;
    int n = i % NN;
    int tn = t_now_p[0], tx = t_next_p[0];
    float a = ac[tn], an = ac[tx];
    float sqrt_recip = sqrtf(1.0f / a);
    float sqrt_recipm1 = sqrtf(1.0f / a - 1.0f);
    float sigma = sqrtf((1.0f - a / an) * (1.0f - an) / (1.0f - a));
    float cc = sqrtf(1.0f - an - sigma * sigma);
    float sqan = sqrtf(an);
    const float2 bt = ((const float2*)boxes_t)[i];
    const float2 bs = ((const float2*)(pb + (size_t)(NH - 1) * BB * NN * 2))[i];
    float2 o;
    if (keep[n]) {
        const float2 nz = ((const float2*)noise)[i];
        float pn0 = (sqrt_recip * bt.x - bs.x) / sqrt_recipm1;
        float pn1 = (sqrt_recip * bt.y - bs.y) / sqrt_recipm1;
        o.x = bs.x * sqan + cc * pn0 + sigma * nz.x;
        o.y = bs.y * sqan + cc * pn1 + sigma * nz.y;
    } else {
        o = ((const float2*)fresh)[i];
    }
    ((float2*)out)[i] = o;
}

// ---------------------------------------------------------------------------
// Bitmask NMS. One block (512 threads) per batch.
//   P1: counting-rank stable descending sort (LDS broadcast reads)
//   P2: per sorted row a, build 500-bit suppress mask (8 u64 words)
//   P3: single-thread register-only greedy closure (no barriers, ~20cy/iter)
// ---------------------------------------------------------------------------
__global__ __launch_bounds__(512) void nms_kernel(const float* __restrict__ pb,
                                                  const float* __restrict__ scores,
                                                  const float* __restrict__ labels,
                                                  float* __restrict__ keep_out) {
    __shared__ float x1u[NN], x2u[NN], wu[NN], scs[NN];
    __shared__ int labu[NN];
    __shared__ int order[NN];
    __shared__ float4 sbox[NN];        // sorted: (x1, x2, w, label-bits)
    __shared__ u64 masks[NN * 8];      // 32 KB suppress bitmasks (sorted domain)
    __shared__ u64 rem_s[8];

    const int b = blockIdx.x;
    const int tid = threadIdx.x;

    const float2* boxes = (const float2*)(pb + (size_t)(NH - 1) * BB * NN * 2) + (size_t)b * NN;
    const float* sc = scores + (size_t)b * NN;
    const float* lb = labels + (size_t)b * NN;

    if (tid < NN) {
        float2 cw = boxes[tid];
        float w = fmaxf(cw.y, 0.0001f);
        x1u[tid] = cw.x - w * 0.5f;
        x2u[tid] = cw.x + w * 0.5f;
        wu[tid] = w;                   // union uses clamped w (matches reference)
        scs[tid] = sc[tid];
        labu[tid] = (int)lb[tid];
    }
    __syncthreads();

    // P1: stable descending rank. scs[j] is wave-uniform -> LDS broadcast (free).
    if (tid < NN) {
        float si = scs[tid];
        int r = 0;
        for (int j = 0; j < NN; ++j) {
            float sj = scs[j];
            r += (sj > si) || (sj == si && j < tid);
        }
        order[r] = tid;
    }
    __syncthreads();

    // gather into sorted order
    if (tid < NN) {
        int i = order[tid];
        sbox[tid] = make_float4(x1u[i], x2u[i], wu[i], __int_as_float(labu[i]));
    }
    __syncthreads();

    // P2: build masks. Thread tid owns sorted row a=tid.
    if (tid < NN) {
        const int a = tid;
        const float4 me = sbox[a];
        const int lk = __float_as_int(me.w);
        const int w0 = a >> 6;
        for (int wd = 0; wd < w0; ++wd) masks[a * 8 + wd] = 0ull;
        for (int wd = w0; wd < 8; ++wd) {
            u64 m = 0ull;
            int b0 = max(a + 1, wd * 64);
            int b1 = min(NN, wd * 64 + 64);
            for (int j = b0; j < b1; ++j) {
                float4 ob = sbox[j];
                if (__float_as_int(ob.w) == lk) {
                    float inter = fmaxf(0.0f, fminf(me.y, ob.y) - fmaxf(me.x, ob.x));
                    float uni = me.z + ob.z - inter;
                    float iou = inter / fmaxf(uni, 1e-9f);   // IEEE div, matches ref
                    if (iou > 0.5f) m |= 1ull << (j & 63);
                }
            }
            masks[a * 8 + wd] = m;
        }
    }
    __syncthreads();

    // P3: sequential greedy closure, registers only. Word w is final after its
    // own i-block (later rows only set bits above themselves).
    if (tid == 0) {
        u64 rem[8] = {0, 0, 0, 0, 0, 0, 0, 0};
        for (int w = 0; w < 8; ++w) {
            u64 curw = rem[w];
            const int i1 = min(NN, w * 64 + 64);
            for (int i = w * 64; i < i1; ++i) {
                // unconditional loads -> pipelineable; conditional OR via mask
                u64 sel = ((curw >> (i & 63)) & 1ull) ? 0ull : ~0ull;
#pragma unroll
                for (int w2 = 0; w2 < 8; ++w2) rem[w2] |= masks[i * 8 + w2] & sel;
                curw = rem[w];
            }
            rem_s[w] = rem[w];
        }
    }
    __syncthreads();

    if (tid < NN) {
        u64 bit = (rem_s[tid >> 6] >> (tid & 63)) & 1ull;
        keep_out[(size_t)b * NN + order[tid]] = bit ? 0.0f : 1.0f;
    }
}

extern "C" void kernel_launch(void* const* d_in, const int* in_sizes, int n_in,
                              void* d_out, int out_size, void* d_ws, size_t ws_size,
                              hipStream_t stream) {
    const float* boxes_t = (const float*)d_in[0];
    const float* pc      = (const float*)d_in[1];
    const float* pb      = (const float*)d_in[2];
    const float* noise   = (const float*)d_in[3];
    const float* fresh   = (const float*)d_in[4];
    const float* ac      = (const float*)d_in[5];
    const int*   t_now   = (const int*)d_in[6];
    const int*   t_next  = (const int*)d_in[7];

    float* out_boxes  = (float*)d_out;                    // 128000
    float* out_scores = out_boxes + (size_t)BB * NN * 2;  // 64000
    float* out_labels = out_scores + (size_t)BB * NN;     // 64000
    float* out_keep   = out_labels + (size_t)BB * NN;     // 64000

    int* keep_ws = (int*)d_ws;  // 500 ints

    scores_labels_keep_kernel<<<(BB * NN) / 64, 256, 0, stream>>>(
        pc, out_scores, out_labels, keep_ws);
    boxes_next_kernel<<<(BB * NN + 255) / 256, 256, 0, stream>>>(
        boxes_t, pb, noise, fresh, ac, t_now, t_next, keep_ws, out_boxes);
    nms_kernel<<<BB, 512, 0, stream>>>(pb, out_scores, out_labels, out_keep);
}

// Round 3
// 235.969 us; speedup vs baseline: 1.5829x; 1.3126x over previous
//
#include <hip/hip_runtime.h>
#include <float.h>

#define BB 128
#define NN 500
#define CC 80
#define NH 6
#define NP 512          // padded N
#define MS 9            // mask row stride in u64 (pad: breaks 32-way bank conflict)

typedef unsigned long long u64;
typedef unsigned int u32;

// ---------------------------------------------------------------------------
// scores/labels/keep fused. 4 threads per row, float4 loads.
// ---------------------------------------------------------------------------
__global__ __launch_bounds__(256) void scores_labels_keep_kernel(
    const float* __restrict__ pc,
    float* __restrict__ scores,
    float* __restrict__ labels,
    int* __restrict__ keep) {
    const int rl = threadIdx.x >> 2;
    const int q = threadIdx.x & 3;
    const int row = blockIdx.x * 64 + rl;
    if (row >= BB * NN) return;

    const float4* base = (const float4*)(pc + (size_t)(NH - 1) * BB * NN * CC);
    float4 v[5];
#pragma unroll
    for (int k = 0; k < 5; ++k) v[k] = base[(size_t)row * 20 + q + 4 * k];

    float m = v[0].x;
#pragma unroll
    for (int k = 0; k < 5; ++k) {
        m = fmaxf(m, v[k].x); m = fmaxf(m, v[k].y);
        m = fmaxf(m, v[k].z); m = fmaxf(m, v[k].w);
    }
    m = fmaxf(m, __shfl_xor(m, 1));
    m = fmaxf(m, __shfl_xor(m, 2));

    float s = 0.0f;
#pragma unroll
    for (int k = 0; k < 5; ++k) {
        s += expf(v[k].x - m); s += expf(v[k].y - m);
        s += expf(v[k].z - m); s += expf(v[k].w - m);
    }
    s += __shfl_xor(s, 1);
    s += __shfl_xor(s, 2);

    float bv = -FLT_MAX; int bc = 1000;
#pragma unroll
    for (int k = 0; k < 5; ++k) {
        const float* vf = (const float*)&v[k];
#pragma unroll
        for (int j = 0; j < 4; ++j) {
            int c = (q + 4 * k) * 4 + j;
            float val = vf[j];
            if (c < CC - 1 && (val > bv || (val == bv && c < bc))) { bv = val; bc = c; }
        }
    }
#pragma unroll
    for (int off = 1; off < 4; off <<= 1) {
        float ov = __shfl_xor(bv, off);
        int oc = __shfl_xor(bc, off);
        if (ov > bv || (ov == bv && oc < bc)) { bv = ov; bc = oc; }
    }

    if (q == 0) {
        scores[row] = expf(bv - m) / s;
        labels[row] = (float)bc;
        if (row < NN) keep[row] = (m > 0.0f) ? 1 : 0;
    }
}

// ---------------------------------------------------------------------------
// boxes_next
// ---------------------------------------------------------------------------
__global__ void boxes_next_kernel(const float* __restrict__ boxes_t,
                                  const float* __restrict__ pb,
                                  const float* __restrict__ noise,
                                  const float* __restrict__ fresh,
                                  const float* __restrict__ ac,
                                  const int* __restrict__ t_now_p,
                                  const int* __restrict__ t_next_p,
                                  const int* __restrict__ keep,
                                  float* __restrict__ out) {
    int i = blockIdx.x * blockDim.x + threadIdx.x;
    if (i >= BB * NN) return;
    int n = i % NN;
    int tn = t_now_p[0], tx = t_next_p[0];
    float a = ac[tn], an = ac[tx];
    float sqrt_recip = sqrtf(1.0f / a);
    float sqrt_recipm1 = sqrtf(1.0f / a - 1.0f);
    float sigma = sqrtf((1.0f - a / an) * (1.0f - an) / (1.0f - a));
    float cc = sqrtf(1.0f - an - sigma * sigma);
    float sqan = sqrtf(an);
    const float2 bt = ((const float2*)boxes_t)[i];
    const float2 bs = ((const float2*)(pb + (size_t)(NH - 1) * BB * NN * 2))[i];
    float2 o;
    if (keep[n]) {
        const float2 nz = ((const float2*)noise)[i];
        float pn0 = (sqrt_recip * bt.x - bs.x) / sqrt_recipm1;
        float pn1 = (sqrt_recip * bt.y - bs.y) / sqrt_recipm1;
        o.x = bs.x * sqan + cc * pn0 + sigma * nz.x;
        o.y = bs.y * sqan + cc * pn1 + sigma * nz.y;
    } else {
        o = ((const float2*)fresh)[i];
    }
    ((float2*)out)[i] = o;
}

// ---------------------------------------------------------------------------
// NMS v3. One block (1024 threads, 16 waves) per batch.
//  P1: counting-rank via float4 LDS broadcasts
//  P2: sorted-domain bitmask build; (a-block, word) tasks, wave-uniform wd
//      -> broadcast j reads; divide gated behind cheap predicate
//  P3: 8-lane register closure with 1-ahead mask prefetch (branchless)
// ---------------------------------------------------------------------------
__global__ __launch_bounds__(1024) void nms_kernel(const float* __restrict__ pb,
                                                   const float* __restrict__ scores,
                                                   const float* __restrict__ labels,
                                                   float* __restrict__ keep_out) {
    __shared__ float4 scs4[NP / 4];      // scores, padded with -FLT_MAX
    __shared__ float4 box4u[NP];         // unsorted (x1,x2,w,label-bits)
    __shared__ float4 sbox4[NP];         // sorted
    __shared__ int order[NP];            // rank -> original index
    __shared__ u64 masks[NN * MS + 16];  // sorted-domain suppress bitmasks (padded stride)
    __shared__ u32 rem_lo[8], rem_hi[8];

    const int b = blockIdx.x;
    const int tid = threadIdx.x;
    float* scs = (float*)scs4;

    const float2* boxes = (const float2*)(pb + (size_t)(NH - 1) * BB * NN * 2) + (size_t)b * NN;
    const float* sc = scores + (size_t)b * NN;
    const float* lb = labels + (size_t)b * NN;

    // P0: prep
    if (tid < NP) {
        if (tid < NN) {
            float2 cw = boxes[tid];
            float w = fmaxf(cw.y, 0.0001f);
            box4u[tid] = make_float4(cw.x - w * 0.5f, cw.x + w * 0.5f, w,
                                     __int_as_float((int)lb[tid]));
            scs[tid] = sc[tid];
        } else {
            box4u[tid] = make_float4(0.f, 0.f, 0.f, __int_as_float(-1));
            scs[tid] = -FLT_MAX;
        }
    }
    __syncthreads();

    // P1: stable descending counting rank (float4 broadcast reads)
    if (tid < NP) {
        float si = scs[tid];
        int r = 0;
        for (int j4 = 0; j4 < NP / 4; ++j4) {
            float4 s4 = scs4[j4];
            int j = j4 * 4;
            r += (s4.x > si) || (s4.x == si && (j + 0) < tid);
            r += (s4.y > si) || (s4.y == si && (j + 1) < tid);
            r += (s4.z > si) || (s4.z == si && (j + 2) < tid);
            r += (s4.w > si) || (s4.w == si && (j + 3) < tid);
        }
        order[r] = tid;
    }
    __syncthreads();

    // gather into sorted order
    if (tid < NP) sbox4[tid] = box4u[order[tid]];
    __syncthreads();

    // P2: build masks. 64 (ablk, wd) pairs; valid if wd >= ablk.
    // Also zero lower-triangle words.
    {
        // zero-fill lower words (wd < a>>6)
        for (int t = tid; t < NN * 8; t += 1024) {
            int a = t >> 3, wd = t & 7;
            if (wd < (a >> 6)) masks[a * MS + wd] = 0ull;
        }
        const int wid = tid >> 6;
        const int lane = tid & 63;
        for (int p = wid; p < 64; p += 16) {
            const int ablk = p >> 3, wd = p & 7;
            if (wd < ablk) continue;
            const int a = ablk * 64 + lane;
            float4 me = (a < NN) ? sbox4[a] : make_float4(0.f, 0.f, 0.f, __int_as_float(-2));
            const int lk = __float_as_int(me.w);
            u64 m = 0ull;
            const int j1 = min(NN, wd * 64 + 64);
            for (int j = wd * 64; j < j1; ++j) {
                float4 ob = sbox4[j];  // wave-uniform -> LDS broadcast
                float inter = fminf(me.y, ob.y) - fmaxf(me.x, ob.x);
                bool pre = (j > a) && (__float_as_int(ob.w) == lk) && (inter > 0.0f);
                if (pre) {  // divide path rarely taken, few active lanes
                    float uni = me.z + ob.z - inter;
                    float iou = inter / fmaxf(uni, 1e-9f);  // IEEE div, matches ref
                    if (iou > 0.5f) m |= 1ull << (j & 63);
                }
            }
            if (a < NN) masks[a * MS + wd] = m;
        }
    }
    __syncthreads();

    // P3: greedy closure, 8-lane parallel, branchless, prefetch-1
    if (tid < 64) {
        const int lane = tid;
        const int lw = lane & 7;
        u32 lo = 0, hi = 0;
        u64 nextm = masks[0 * MS + lw];
        for (int i = 0; i < NN; ++i) {
            u64 mw = nextm;
            nextm = masks[(i + 1) * MS + lw];  // padded array, safe at i=NN-1
            u32 colo = __builtin_amdgcn_readlane(lo, i >> 6);
            u32 cohi = __builtin_amdgcn_readlane(hi, i >> 6);
            u32 bit = (i & 32) ? ((cohi >> (i & 31)) & 1u) : ((colo >> (i & 31)) & 1u);
            u32 sel = bit ? 0u : 0xFFFFFFFFu;   // suppressed row contributes nothing
            lo |= (u32)mw & sel;
            hi |= (u32)(mw >> 32) & sel;
        }
        if (lane < 8) { rem_lo[lane] = lo; rem_hi[lane] = hi; }
    }
    __syncthreads();

    if (tid < NN) {
        u32 word = (tid & 32) ? rem_hi[tid >> 6] : rem_lo[tid >> 6];
        u32 bit = (word >> (tid & 31)) & 1u;
        keep_out[(size_t)b * NN + order[tid]] = bit ? 0.0f : 1.0f;
    }
}

extern "C" void kernel_launch(void* const* d_in, const int* in_sizes, int n_in,
                              void* d_out, int out_size, void* d_ws, size_t ws_size,
                              hipStream_t stream) {
    const float* boxes_t = (const float*)d_in[0];
    const float* pc      = (const float*)d_in[1];
    const float* pb      = (const float*)d_in[2];
    const float* noise   = (const float*)d_in[3];
    const float* fresh   = (const float*)d_in[4];
    const float* ac      = (const float*)d_in[5];
    const int*   t_now   = (const int*)d_in[6];
    const int*   t_next  = (const int*)d_in[7];

    float* out_boxes  = (float*)d_out;                    // 128000
    float* out_scores = out_boxes + (size_t)BB * NN * 2;  // 64000
    float* out_labels = out_scores + (size_t)BB * NN;     // 64000
    float* out_keep   = out_labels + (size_t)BB * NN;     // 64000

    int* keep_ws = (int*)d_ws;

    scores_labels_keep_kernel<<<(BB * NN) / 64, 256, 0, stream>>>(
        pc, out_scores, out_labels, keep_ws);
    boxes_next_kernel<<<(BB * NN + 255) / 256, 256, 0, stream>>>(
        boxes_t, pb, noise, fresh, ac, t_now, t_next, keep_ws, out_boxes);
    nms_kernel<<<BB, 1024, 0, stream>>>(pb, out_scores, out_labels, out_keep);
}

// Round 4
// 221.885 us; speedup vs baseline: 1.6834x; 1.0635x over previous
//
#include <hip/hip_runtime.h>
#include <float.h>

#define BB 128
#define NN 500
#define CC 80
#define NH 6
#define NP 512          // padded N

typedef unsigned long long u64;
typedef unsigned int u32;

// ---------------------------------------------------------------------------
// scores/labels/keep fused. 4 threads per row, float4 loads.
// ---------------------------------------------------------------------------
__global__ __launch_bounds__(256) void scores_labels_keep_kernel(
    const float* __restrict__ pc,
    float* __restrict__ scores,
    float* __restrict__ labels,
    int* __restrict__ keep) {
    const int rl = threadIdx.x >> 2;
    const int q = threadIdx.x & 3;
    const int row = blockIdx.x * 64 + rl;
    if (row >= BB * NN) return;

    const float4* base = (const float4*)(pc + (size_t)(NH - 1) * BB * NN * CC);
    float4 v[5];
#pragma unroll
    for (int k = 0; k < 5; ++k) v[k] = base[(size_t)row * 20 + q + 4 * k];

    float m = v[0].x;
#pragma unroll
    for (int k = 0; k < 5; ++k) {
        m = fmaxf(m, v[k].x); m = fmaxf(m, v[k].y);
        m = fmaxf(m, v[k].z); m = fmaxf(m, v[k].w);
    }
    m = fmaxf(m, __shfl_xor(m, 1));
    m = fmaxf(m, __shfl_xor(m, 2));

    float s = 0.0f;
#pragma unroll
    for (int k = 0; k < 5; ++k) {
        s += expf(v[k].x - m); s += expf(v[k].y - m);
        s += expf(v[k].z - m); s += expf(v[k].w - m);
    }
    s += __shfl_xor(s, 1);
    s += __shfl_xor(s, 2);

    float bv = -FLT_MAX; int bc = 1000;
#pragma unroll
    for (int k = 0; k < 5; ++k) {
        const float* vf = (const float*)&v[k];
#pragma unroll
        for (int j = 0; j < 4; ++j) {
            int c = (q + 4 * k) * 4 + j;
            float val = vf[j];
            if (c < CC - 1 && (val > bv || (val == bv && c < bc))) { bv = val; bc = c; }
        }
    }
#pragma unroll
    for (int off = 1; off < 4; off <<= 1) {
        float ov = __shfl_xor(bv, off);
        int oc = __shfl_xor(bc, off);
        if (ov > bv || (ov == bv && oc < bc)) { bv = ov; bc = oc; }
    }

    if (q == 0) {
        scores[row] = expf(bv - m) / s;
        labels[row] = (float)bc;
        if (row < NN) keep[row] = (m > 0.0f) ? 1 : 0;
    }
}

// ---------------------------------------------------------------------------
// boxes_next
// ---------------------------------------------------------------------------
__global__ void boxes_next_kernel(const float* __restrict__ boxes_t,
                                  const float* __restrict__ pb,
                                  const float* __restrict__ noise,
                                  const float* __restrict__ fresh,
                                  const float* __restrict__ ac,
                                  const int* __restrict__ t_now_p,
                                  const int* __restrict__ t_next_p,
                                  const int* __restrict__ keep,
                                  float* __restrict__ out) {
    int i = blockIdx.x * blockDim.x + threadIdx.x;
    if (i >= BB * NN) return;
    int n = i % NN;
    int tn = t_now_p[0], tx = t_next_p[0];
    float a = ac[tn], an = ac[tx];
    float sqrt_recip = sqrtf(1.0f / a);
    float sqrt_recipm1 = sqrtf(1.0f / a - 1.0f);
    float sigma = sqrtf((1.0f - a / an) * (1.0f - an) / (1.0f - a));
    float cc = sqrtf(1.0f - an - sigma * sigma);
    float sqan = sqrtf(an);
    const float2 bt = ((const float2*)boxes_t)[i];
    const float2 bs = ((const float2*)(pb + (size_t)(NH - 1) * BB * NN * 2))[i];
    float2 o;
    if (keep[n]) {
        const float2 nz = ((const float2*)noise)[i];
        float pn0 = (sqrt_recip * bt.x - bs.x) / sqrt_recipm1;
        float pn1 = (sqrt_recip * bt.y - bs.y) / sqrt_recipm1;
        o.x = bs.x * sqan + cc * pn0 + sigma * nz.x;
        o.y = bs.y * sqan + cc * pn1 + sigma * nz.y;
    } else {
        o = ((const float2*)fresh)[i];
    }
    ((float2*)out)[i] = o;
}

// ---------------------------------------------------------------------------
// NMS v4: label-bucketed greedy. One block (512 threads, 8 waves) per batch.
// Per-label greedy in label-local score order == global-order greedy, because
// suppression only couples same-label pairs. Pair work: sum n_l^2 ~ 3.6k
// instead of 125k dense tests.
//  P1: stable counting rank (float4 LDS broadcasts)
//  P2: u8-packed sorted labels -> within-bucket rank via uint4 broadcast
//      scans + LDS histogram + serial prefix -> scatter member lists
//  P3: per-bucket serial greedy; buckets striped across 8 waves
// ---------------------------------------------------------------------------
__global__ __launch_bounds__(512) void nms_kernel(const float* __restrict__ pb,
                                                  const float* __restrict__ scores,
                                                  const float* __restrict__ labels,
                                                  float* __restrict__ keep_out) {
    __shared__ float4 scs4[NP / 4];        // scores (padded -FLT_MAX)
    __shared__ float4 box4u[NP];           // unsorted (x1,x2,w,label-bits)
    __shared__ float4 sbox4[NP];           // sorted
    __shared__ int order[NP];              // rank -> original index
    __shared__ unsigned char lab8[NP];     // sorted labels, u8 (pad=255)
    __shared__ short brank_s[NP];          // rank within bucket
    __shared__ short member[NP];           // bucket-ordered sorted-rank lists
    __shared__ int hist[CC];               // bucket sizes
    __shared__ int boff[CC];               // bucket offsets
    __shared__ unsigned char supp[NP];

    const int b = blockIdx.x;
    const int tid = threadIdx.x;
    float* scs = (float*)scs4;

    const float2* boxes = (const float2*)(pb + (size_t)(NH - 1) * BB * NN * 2) + (size_t)b * NN;
    const float* sc = scores + (size_t)b * NN;
    const float* lb = labels + (size_t)b * NN;

    // P0: prep
    if (tid < CC) hist[tid] = 0;
    if (tid < NN) {
        float2 cw = boxes[tid];
        float w = fmaxf(cw.y, 0.0001f);
        box4u[tid] = make_float4(cw.x - w * 0.5f, cw.x + w * 0.5f, w,
                                 __int_as_float((int)lb[tid]));
        scs[tid] = sc[tid];
    } else {
        box4u[tid] = make_float4(0.f, 0.f, 0.f, __int_as_float(255));
        scs[tid] = -FLT_MAX;
    }
    supp[tid] = 0;
    __syncthreads();

    // P1: stable descending counting rank (float4 broadcast reads)
    {
        float si = scs[tid];
        int r = 0;
        for (int j4 = 0; j4 < NP / 4; ++j4) {
            float4 s4 = scs4[j4];
            int j = j4 * 4;
            r += (s4.x > si) || (s4.x == si && (j + 0) < tid);
            r += (s4.y > si) || (s4.y == si && (j + 1) < tid);
            r += (s4.z > si) || (s4.z == si && (j + 2) < tid);
            r += (s4.w > si) || (s4.w == si && (j + 3) < tid);
        }
        order[r] = tid;
    }
    __syncthreads();

    // gather into sorted order
    {
        float4 v = box4u[order[tid]];
        sbox4[tid] = v;
        lab8[tid] = (unsigned char)__float_as_int(v.w);
    }
    __syncthreads();

    // P2: within-bucket rank + histogram
    if (tid < NN) {
        const u32 myl = lab8[tid];
        int cnt = 0;
        const uint4* l16 = (const uint4*)lab8;
        const int nc = (tid >> 4) + 1;
        for (int cI = 0; cI < nc; ++cI) {
            uint4 c = l16[cI];   // wave-mostly-uniform -> broadcast
            int base = cI * 16;
#pragma unroll
            for (int byi = 0; byi < 4; ++byi) {
                cnt += (base + byi      < tid) && (((c.x >> (8 * byi)) & 0xFF) == myl);
                cnt += (base + 4 + byi  < tid) && (((c.y >> (8 * byi)) & 0xFF) == myl);
                cnt += (base + 8 + byi  < tid) && (((c.z >> (8 * byi)) & 0xFF) == myl);
                cnt += (base + 12 + byi < tid) && (((c.w >> (8 * byi)) & 0xFF) == myl);
            }
        }
        brank_s[tid] = (short)cnt;
        atomicAdd(&hist[myl], 1);
    }
    __syncthreads();
    if (tid == 0) {
        int s = 0;
        for (int l = 0; l < CC; ++l) { boff[l] = s; s += hist[l]; }
    }
    __syncthreads();
    if (tid < NN) member[boff[lab8[tid]] + brank_s[tid]] = (short)tid;
    __syncthreads();

    // P3: per-bucket greedy; bucket l -> wave (l&7), lane (l>>3)
    {
        const int lane = tid & 63;
        const int wv = tid >> 6;
        const int l = lane * 8 + wv;
        if (l < CC) {
            const int n = hist[l], off = boff[l];
            for (int p = 0; p < n - 1; ++p) {
                const int rp = member[off + p];
                if (supp[rp]) continue;
                const float4 bp = sbox4[rp];
                for (int q = p + 1; q < n; ++q) {
                    const int rq = member[off + q];
                    if (supp[rq]) continue;
                    const float4 bq = sbox4[rq];
                    float inter = fminf(bp.y, bq.y) - fmaxf(bp.x, bq.x);
                    if (inter > 0.0f) {
                        float uni = bp.z + bq.z - inter;
                        float iou = inter / fmaxf(uni, 1e-9f);  // IEEE div, matches ref
                        if (iou > 0.5f) supp[rq] = 1;
                    }
                }
            }
        }
    }
    __syncthreads();

    if (tid < NN) {
        keep_out[(size_t)b * NN + order[tid]] = supp[tid] ? 0.0f : 1.0f;
    }
}

extern "C" void kernel_launch(void* const* d_in, const int* in_sizes, int n_in,
                              void* d_out, int out_size, void* d_ws, size_t ws_size,
                              hipStream_t stream) {
    const float* boxes_t = (const float*)d_in[0];
    const float* pc      = (const float*)d_in[1];
    const float* pb      = (const float*)d_in[2];
    const float* noise   = (const float*)d_in[3];
    const float* fresh   = (const float*)d_in[4];
    const float* ac      = (const float*)d_in[5];
    const int*   t_now   = (const int*)d_in[6];
    const int*   t_next  = (const int*)d_in[7];

    float* out_boxes  = (float*)d_out;                    // 128000
    float* out_scores = out_boxes + (size_t)BB * NN * 2;  // 64000
    float* out_labels = out_scores + (size_t)BB * NN;     // 64000
    float* out_keep   = out_labels + (size_t)BB * NN;     // 64000

    int* keep_ws = (int*)d_ws;

    scores_labels_keep_kernel<<<(BB * NN) / 64, 256, 0, stream>>>(
        pc, out_scores, out_labels, keep_ws);
    boxes_next_kernel<<<(BB * NN + 255) / 256, 256, 0, stream>>>(
        boxes_t, pb, noise, fresh, ac, t_now, t_next, keep_ws, out_boxes);
    nms_kernel<<<BB, 512, 0, stream>>>(pb, out_scores, out_labels, out_keep);
}

// Round 5
// 214.698 us; speedup vs baseline: 1.7397x; 1.0335x over previous
//
#include <hip/hip_runtime.h>
#include <float.h>

#define BB 128
#define NN 500
#define CC 80
#define NH 6
#define NP 512          // padded N

typedef unsigned long long u64;
typedef unsigned int u32;

// ---------------------------------------------------------------------------
// scores/labels/keep fused. 4 threads per row, float4 loads.
// ---------------------------------------------------------------------------
__global__ __launch_bounds__(256) void scores_labels_keep_kernel(
    const float* __restrict__ pc,
    float* __restrict__ scores,
    float* __restrict__ labels,
    int* __restrict__ keep) {
    const int rl = threadIdx.x >> 2;
    const int q = threadIdx.x & 3;
    const int row = blockIdx.x * 64 + rl;
    if (row >= BB * NN) return;

    const float4* base = (const float4*)(pc + (size_t)(NH - 1) * BB * NN * CC);
    float4 v[5];
#pragma unroll
    for (int k = 0; k < 5; ++k) v[k] = base[(size_t)row * 20 + q + 4 * k];

    float m = v[0].x;
#pragma unroll
    for (int k = 0; k < 5; ++k) {
        m = fmaxf(m, v[k].x); m = fmaxf(m, v[k].y);
        m = fmaxf(m, v[k].z); m = fmaxf(m, v[k].w);
    }
    m = fmaxf(m, __shfl_xor(m, 1));
    m = fmaxf(m, __shfl_xor(m, 2));

    float s = 0.0f;
#pragma unroll
    for (int k = 0; k < 5; ++k) {
        s += expf(v[k].x - m); s += expf(v[k].y - m);
        s += expf(v[k].z - m); s += expf(v[k].w - m);
    }
    s += __shfl_xor(s, 1);
    s += __shfl_xor(s, 2);

    float bv = -FLT_MAX; int bc = 1000;
#pragma unroll
    for (int k = 0; k < 5; ++k) {
        const float* vf = (const float*)&v[k];
#pragma unroll
        for (int j = 0; j < 4; ++j) {
            int c = (q + 4 * k) * 4 + j;
            float val = vf[j];
            if (c < CC - 1 && (val > bv || (val == bv && c < bc))) { bv = val; bc = c; }
        }
    }
#pragma unroll
    for (int off = 1; off < 4; off <<= 1) {
        float ov = __shfl_xor(bv, off);
        int oc = __shfl_xor(bc, off);
        if (ov > bv || (ov == bv && oc < bc)) { bv = ov; bc = oc; }
    }

    if (q == 0) {
        scores[row] = expf(bv - m) / s;
        labels[row] = (float)bc;
        if (row < NN) keep[row] = (m > 0.0f) ? 1 : 0;
    }
}

// ---------------------------------------------------------------------------
// NMS v5 + fused boxes_next. One block (512 threads, 8 waves) per batch.
//  P0: load boxes/scores/labels to LDS; ALSO compute boxes_next for this
//      batch (independent elementwise work, overlaps with sort phases)
//  P1: stable counting rank (float4 LDS broadcasts)
//  P2: within-bucket rank (uint4 byte scans) + histogram + WAVE-SCAN prefix
//  P3: wave-per-bucket register greedy: members in lanes, box p broadcast
//      via readlane, alive-mask via __ballot — no LDS in the loop
// ---------------------------------------------------------------------------
__global__ __launch_bounds__(512) void nms_kernel(const float* __restrict__ pb,
                                                  const float* __restrict__ scores,
                                                  const float* __restrict__ labels,
                                                  const float* __restrict__ boxes_t,
                                                  const float* __restrict__ noise,
                                                  const float* __restrict__ fresh,
                                                  const float* __restrict__ ac,
                                                  const int* __restrict__ t_now_p,
                                                  const int* __restrict__ t_next_p,
                                                  const int* __restrict__ keep_ws,
                                                  float* __restrict__ out_boxes,
                                                  float* __restrict__ keep_out) {
    __shared__ float4 scs4[NP / 4];        // scores (padded -FLT_MAX)
    __shared__ float4 box4u[NP];           // unsorted (x1,x2,w,label-bits)
    __shared__ float4 sbox4[NP];           // sorted
    __shared__ int order[NP];              // rank -> original index
    __shared__ unsigned char lab8[NP];     // sorted labels, u8 (pad=255)
    __shared__ short brank_s[NP];          // rank within bucket
    __shared__ short member[NP];           // bucket-ordered sorted-rank lists
    __shared__ int hist[CC];               // bucket sizes
    __shared__ int boff[CC];               // bucket offsets
    __shared__ unsigned char supp[NP];

    const int b = blockIdx.x;
    const int tid = threadIdx.x;
    float* scs = (float*)scs4;

    const float2* boxes = (const float2*)(pb + (size_t)(NH - 1) * BB * NN * 2) + (size_t)b * NN;
    const float* sc = scores + (size_t)b * NN;
    const float* lb = labels + (size_t)b * NN;

    // P0: prep + fused boxes_next for this batch
    if (tid < CC) hist[tid] = 0;
    supp[tid] = 0;
    if (tid < NN) {
        float2 cw = boxes[tid];   // boxes_start[b][tid]
        float w = fmaxf(cw.y, 0.0001f);
        box4u[tid] = make_float4(cw.x - w * 0.5f, cw.x + w * 0.5f, w,
                                 __int_as_float((int)lb[tid]));
        scs[tid] = sc[tid];

        // ---- fused boxes_next ----
        {
            const size_t i = (size_t)b * NN + tid;
            int tn = t_now_p[0], tx = t_next_p[0];
            float a = ac[tn], an = ac[tx];
            float sqrt_recip = sqrtf(1.0f / a);
            float sqrt_recipm1 = sqrtf(1.0f / a - 1.0f);
            float sigma = sqrtf((1.0f - a / an) * (1.0f - an) / (1.0f - a));
            float ccf = sqrtf(1.0f - an - sigma * sigma);
            float sqan = sqrtf(an);
            const float2 bt = ((const float2*)boxes_t)[i];
            float2 o;
            if (keep_ws[tid]) {
                const float2 nz = ((const float2*)noise)[i];
                float pn0 = (sqrt_recip * bt.x - cw.x) / sqrt_recipm1;
                float pn1 = (sqrt_recip * bt.y - cw.y) / sqrt_recipm1;
                o.x = cw.x * sqan + ccf * pn0 + sigma * nz.x;
                o.y = cw.y * sqan + ccf * pn1 + sigma * nz.y;
            } else {
                o = ((const float2*)fresh)[i];
            }
            ((float2*)out_boxes)[i] = o;
        }
    } else {
        box4u[tid] = make_float4(0.f, 0.f, 0.f, __int_as_float(255));
        scs[tid] = -FLT_MAX;
    }
    __syncthreads();

    // P1: stable descending counting rank (float4 broadcast reads)
    {
        float si = scs[tid];
        int r = 0;
        for (int j4 = 0; j4 < NP / 4; ++j4) {
            float4 s4 = scs4[j4];
            int j = j4 * 4;
            r += (s4.x > si) || (s4.x == si && (j + 0) < tid);
            r += (s4.y > si) || (s4.y == si && (j + 1) < tid);
            r += (s4.z > si) || (s4.z == si && (j + 2) < tid);
            r += (s4.w > si) || (s4.w == si && (j + 3) < tid);
        }
        order[r] = tid;
    }
    __syncthreads();

    // gather into sorted order
    {
        float4 v = box4u[order[tid]];
        sbox4[tid] = v;
        lab8[tid] = (unsigned char)__float_as_int(v.w);
    }
    __syncthreads();

    // P2a: within-bucket rank + histogram
    if (tid < NN) {
        const u32 myl = lab8[tid];
        int cnt = 0;
        const uint4* l16 = (const uint4*)lab8;
        const int nc = (tid >> 4) + 1;
        for (int cI = 0; cI < nc; ++cI) {
            uint4 c = l16[cI];   // wave-mostly-uniform -> broadcast
            int base = cI * 16;
#pragma unroll
            for (int byi = 0; byi < 4; ++byi) {
                cnt += (base + byi      < tid) && (((c.x >> (8 * byi)) & 0xFF) == myl);
                cnt += (base + 4 + byi  < tid) && (((c.y >> (8 * byi)) & 0xFF) == myl);
                cnt += (base + 8 + byi  < tid) && (((c.z >> (8 * byi)) & 0xFF) == myl);
                cnt += (base + 12 + byi < tid) && (((c.w >> (8 * byi)) & 0xFF) == myl);
            }
        }
        brank_s[tid] = (short)cnt;
        atomicAdd(&hist[myl], 1);
    }
    __syncthreads();

    // P2b: exclusive prefix over 80 bins — wave 0 shuffle scan (2 elems/lane)
    if (tid < 64) {
        int a = (tid < CC) ? hist[tid] : 0;
        int b2 = (tid < CC - 64) ? hist[64 + tid] : 0;
        int sa = a;
#pragma unroll
        for (int d = 1; d < 64; d <<= 1) {
            int t = __shfl_up(sa, d);
            if ((int)tid >= d) sa += t;
        }
        int totalA = __shfl(sa, 63);
        int sb = b2;
#pragma unroll
        for (int d = 1; d < 64; d <<= 1) {
            int t = __shfl_up(sb, d);
            if ((int)tid >= d) sb += t;
        }
        if (tid < CC) boff[tid] = sa - a;
        if (tid < CC - 64) boff[64 + tid] = sb - b2 + totalA;
    }
    __syncthreads();

    if (tid < NN) member[boff[lab8[tid]] + brank_s[tid]] = (short)tid;
    __syncthreads();

    // P3: wave-per-bucket register greedy
    {
        const int wv = tid >> 6;
        const int lane = tid & 63;
        for (int l = wv; l < CC; l += 8) {
            const int n = hist[l];         // wave-uniform
            if (n <= 1) continue;
            const int off = boff[l];
            if (n <= 64) {
                const bool valid = lane < n;
                int rq = 0;
                float x1 = 0.f, x2 = 0.f, ww = 0.f;
                if (valid) {
                    rq = member[off + lane];
                    float4 v = sbox4[rq];
                    x1 = v.x; x2 = v.y; ww = v.z;
                }
                bool sup = false;
                for (int p = 0; p < n - 1; ++p) {
                    u64 smask = __ballot(sup);
                    bool pAlive = ((smask >> p) & 1ull) == 0ull;
                    float bx1 = __int_as_float(__builtin_amdgcn_readlane(__float_as_int(x1), p));
                    float bx2 = __int_as_float(__builtin_amdgcn_readlane(__float_as_int(x2), p));
                    float bw  = __int_as_float(__builtin_amdgcn_readlane(__float_as_int(ww), p));
                    float inter = fmaxf(0.0f, fminf(bx2, x2) - fmaxf(bx1, x1));
                    float uni = bw + ww - inter;
                    float iou = inter / fmaxf(uni, 1e-9f);  // IEEE div, matches ref
                    sup = sup || (pAlive && valid && (lane > p) && (iou > 0.5f));
                }
                if (valid && sup) supp[rq] = 1;
            } else {
                // generic fallback (buckets >64 never occur for these inputs)
                if (lane == 0) {
                    for (int p = 0; p < n - 1; ++p) {
                        int rp = member[off + p];
                        if (supp[rp]) continue;
                        float4 bp = sbox4[rp];
                        for (int q2 = p + 1; q2 < n; ++q2) {
                            int rqq = member[off + q2];
                            if (supp[rqq]) continue;
                            float4 bq = sbox4[rqq];
                            float inter = fmaxf(0.0f, fminf(bp.y, bq.y) - fmaxf(bp.x, bq.x));
                            float uni = bp.z + bq.z - inter;
                            float iou = inter / fmaxf(uni, 1e-9f);
                            if (iou > 0.5f) supp[rqq] = 1;
                        }
                    }
                }
            }
        }
    }
    __syncthreads();

    if (tid < NN) {
        keep_out[(size_t)b * NN + order[tid]] = supp[tid] ? 0.0f : 1.0f;
    }
}

extern "C" void kernel_launch(void* const* d_in, const int* in_sizes, int n_in,
                              void* d_out, int out_size, void* d_ws, size_t ws_size,
                              hipStream_t stream) {
    const float* boxes_t = (const float*)d_in[0];
    const float* pc      = (const float*)d_in[1];
    const float* pb      = (const float*)d_in[2];
    const float* noise   = (const float*)d_in[3];
    const float* fresh   = (const float*)d_in[4];
    const float* ac      = (const float*)d_in[5];
    const int*   t_now   = (const int*)d_in[6];
    const int*   t_next  = (const int*)d_in[7];

    float* out_boxes  = (float*)d_out;                    // 128000
    float* out_scores = out_boxes + (size_t)BB * NN * 2;  // 64000
    float* out_labels = out_scores + (size_t)BB * NN;     // 64000
    float* out_keep   = out_labels + (size_t)BB * NN;     // 64000

    int* keep_ws = (int*)d_ws;

    scores_labels_keep_kernel<<<(BB * NN) / 64, 256, 0, stream>>>(
        pc, out_scores, out_labels, keep_ws);
    nms_kernel<<<BB, 512, 0, stream>>>(pb, out_scores, out_labels,
                                       boxes_t, noise, fresh, ac, t_now, t_next,
                                       keep_ws, out_boxes, out_keep);
}